// Round 3
// baseline (539.738 us; speedup 1.0000x reference)
//
#include <hip/hip_runtime.h>
#include <math.h>

// KAN attention: two spline-edge reductions (q,k branches) + bias + softmax(dim=8).
// batch=8, act_in=act_out=2048, C=8 coeffs/edge, N=4.19M edges/branch.
// HBM floor: coef_q+coef_k (268 MB) + mask_q/mask_k/scale_base/scale_sp read
// once (67 MB) = ~335 MB  ->  ~53 us at 6.3 TB/s achievable.
//
// R2 -> R3: R2 was latency-bound (870 GB/s, occ 21%): short-lived blocks, two
// sync-drain phases per branch. Now: 512 fully-resident blocks (2/CU), both
// branches merged (B staged to LDS once, scales read once), o-dimension
// streamed in 8 software-pipelined steps with double-buffered register
// prefetch -- loads for step s+1 in flight during compute of step s, no
// barriers in the main loop.

#define ACT 2048
#define BATCH 8
#define IBLK 128               // i per block
#define NIC (ACT / IBLK)       // 16 i-chunks
#define OSTEP 8                // o per step
#define STEPS 8                // steps per block
#define OBLK (OSTEP * STEPS)   // 64 o per block
#define NOB (ACT / OBLK)       // 32 o-blocks

__device__ __forceinline__ float dot4(const float4& a, const float4& b) {
  float r = a.x * b.x;
  r = fmaf(a.y, b.y, r);
  r = fmaf(a.z, b.z, r);
  r = fmaf(a.w, b.w, r);
  return r;
}

// ---------------------------------------------------------------------------
// Kernel 1: B-spline basis (Cox-de Boor, k=3, 12 uniform knots at -2.2+0.4j)
// and silu(x) for all (b,i) of both branches.
// Layout (for coalesced LDS staging + conflict-free LDS reads):
//   B[ic][b*2+h][il]  as float4   (ic=i/128, h=coef half, il=i%128)
//   base[ic][b][il]   as float
// ---------------------------------------------------------------------------
__global__ void kan_precompute(const float* __restrict__ q, const float* __restrict__ k,
                               float4* __restrict__ Bq, float4* __restrict__ Bk,
                               float* __restrict__ baseq, float* __restrict__ basek) {
  int tid = blockIdx.x * blockDim.x + threadIdx.x;
  if (tid >= ACT * BATCH) return;
  int il = tid & (IBLK - 1);
  int b = (tid >> 7) & 7;
  int ic = tid >> 10;
  int i = ic * IBLK + il;
  const float t0 = -2.2f;
  const float h = 0.4f;
  for (int br = 0; br < 2; ++br) {
    const float* xsrc = br ? k : q;
    float4* Bdst = br ? Bk : Bq;
    float* basedst = br ? basek : baseq;
    float x = xsrc[(size_t)b * ACT + i];
    float Bv[11];
#pragma unroll
    for (int j = 0; j < 11; ++j) {
      float tj = t0 + h * (float)j;
      float tj1 = t0 + h * (float)(j + 1);
      Bv[j] = (x >= tj && x < tj1) ? 1.0f : 0.0f;
    }
#pragma unroll
    for (int d = 1; d <= 3; ++d) {
      float inv = 1.0f / (h * (float)d);
#pragma unroll
      for (int j = 0; j + d < 11; ++j) {
        float tj = t0 + h * (float)j;
        float tjd1 = t0 + h * (float)(j + d + 1);
        Bv[j] = (x - tj) * inv * Bv[j] + (tjd1 - x) * inv * Bv[j + 1];
      }
    }
    Bdst[((size_t)ic * 16 + b * 2 + 0) * IBLK + il] = make_float4(Bv[0], Bv[1], Bv[2], Bv[3]);
    Bdst[((size_t)ic * 16 + b * 2 + 1) * IBLK + il] = make_float4(Bv[4], Bv[5], Bv[6], Bv[7]);
    basedst[((size_t)ic * 8 + b) * IBLK + il] = x / (1.0f + expf(-x));
  }
}

// ---------------------------------------------------------------------------
// Kernel 2: main reduction. 512 blocks x 512 threads, all resident (2/CU).
// Block = (ic: 128 i) x (64 o in 8 pipelined steps of 8).
// Thread: i = t&127, og = t>>7 (0..3), owns 2 o per step.
// B/base for BOTH branches staged to LDS once (72 KB, one sync), then the
// o-stream runs with double-buffered register prefetch and no barriers.
// ---------------------------------------------------------------------------
__global__ __launch_bounds__(512, 4) void kan_main(
    const float* __restrict__ coef_q, const float* __restrict__ coef_k,
    const float* __restrict__ scale_base, const float* __restrict__ scale_sp,
    const float* __restrict__ mask_q, const float* __restrict__ mask_k,
    const float4* __restrict__ Bq, const float4* __restrict__ Bk,
    const float* __restrict__ baseq, const float* __restrict__ basek,
    float* __restrict__ y) {
  __shared__ float4 Bs[2][16 * IBLK];   // [branch][(b*2+h)*128 + il]
  __shared__ float bas[2][8 * IBLK];    // [branch][b*128 + il]

  const int t = threadIdx.x;
  const int ob = blockIdx.x / NIC;
  const int ic = blockIdx.x - ob * NIC;
  const int o0 = ob * OBLK;
  const int i = t & (IBLK - 1);
  const int og = t >> 7;                // 0..3
  const int ibase = ic * IBLK + i;

  // ---- stage B/base for both branches (once per block) ----
  {
    const float4* srcq = Bq + (size_t)ic * 16 * IBLK;
    const float4* srck = Bk + (size_t)ic * 16 * IBLK;
#pragma unroll
    for (int r = 0; r < 4; ++r) {
      Bs[0][r * 512 + t] = srcq[r * 512 + t];
      Bs[1][r * 512 + t] = srck[r * 512 + t];
    }
    if (t < 256) {
      reinterpret_cast<float4*>(bas[0])[t] =
          reinterpret_cast<const float4*>(baseq + (size_t)ic * 8 * IBLK)[t];
    } else {
      reinterpret_cast<float4*>(bas[1])[t - 256] =
          reinterpret_cast<const float4*>(basek + (size_t)ic * 8 * IBLK)[t - 256];
    }
  }
  __syncthreads();

  // ---- pipelined o-stream ----
  float4 cq[2][2][2], ck[2][2][2];      // [buf][os][half]
  float sc[2][2][4];                    // [buf][os][mq,mk,sb,ss]

#define LOAD_STEP(BUF, S)                                                    \
  {                                                                          \
    _Pragma("unroll") for (int os = 0; os < 2; ++os) {                       \
      const size_t e =                                                       \
          ((size_t)(o0 + (S) * OSTEP + og * 2 + os)) * ACT + (size_t)ibase;  \
      const float4* cpq = reinterpret_cast<const float4*>(coef_q + e * 8);   \
      const float4* cpk = reinterpret_cast<const float4*>(coef_k + e * 8);   \
      cq[BUF][os][0] = cpq[0];                                               \
      cq[BUF][os][1] = cpq[1];                                               \
      ck[BUF][os][0] = cpk[0];                                               \
      ck[BUF][os][1] = cpk[1];                                               \
      sc[BUF][os][0] = mask_q[e];                                            \
      sc[BUF][os][1] = mask_k[e];                                            \
      sc[BUF][os][2] = scale_base[e];                                        \
      sc[BUF][os][3] = scale_sp[e];                                          \
    }                                                                        \
  }

  LOAD_STEP(0, 0)

#pragma unroll
  for (int s = 0; s < STEPS; ++s) {
    const int cur = s & 1;
    if (s + 1 < STEPS) LOAD_STEP(((s + 1) & 1), s + 1)

    float acc[2][BATCH];
#pragma unroll
    for (int os = 0; os < 2; ++os)
#pragma unroll
      for (int b = 0; b < BATCH; ++b) acc[os][b] = 0.0f;

    float vbq[2], vsq[2], vbk[2], vsk[2];
#pragma unroll
    for (int os = 0; os < 2; ++os) {
      vbq[os] = sc[cur][os][0] * sc[cur][os][2];
      vsq[os] = sc[cur][os][0] * sc[cur][os][3];
      vbk[os] = sc[cur][os][1] * sc[cur][os][2];
      vsk[os] = sc[cur][os][1] * sc[cur][os][3];
    }

#pragma unroll
    for (int b = 0; b < BATCH; ++b) {
      const float4 Bq0 = Bs[0][(b * 2 + 0) * IBLK + i];
      const float4 Bq1 = Bs[0][(b * 2 + 1) * IBLK + i];
      const float4 Bk0 = Bs[1][(b * 2 + 0) * IBLK + i];
      const float4 Bk1 = Bs[1][(b * 2 + 1) * IBLK + i];
      const float bsq = bas[0][b * IBLK + i];
      const float bsk = bas[1][b * IBLK + i];
#pragma unroll
      for (int os = 0; os < 2; ++os) {
        float dq = dot4(Bq0, cq[cur][os][0]) + dot4(Bq1, cq[cur][os][1]);
        float dk = dot4(Bk0, ck[cur][os][0]) + dot4(Bk1, ck[cur][os][1]);
        float a = acc[os][b];
        a = fmaf(vsq[os], dq, a);
        a = fmaf(vsk[os], dk, a);
        a = fmaf(vbq[os], bsq, a);
        a = fmaf(vbk[os], bsk, a);
        acc[os][b] = a;
      }
    }

    // reduce over the 64-lane i dimension, one atomic per (wave, os, b)
#pragma unroll
    for (int os = 0; os < 2; ++os) {
#pragma unroll
      for (int b = 0; b < BATCH; ++b) {
        float v = acc[os][b];
#pragma unroll
        for (int off = 32; off > 0; off >>= 1) v += __shfl_down(v, off);
        if ((t & 63) == 0)
          atomicAdd(&y[(size_t)b * ACT + (size_t)(o0 + s * OSTEP + og * 2 + os)], v);
      }
    }
  }
#undef LOAD_STEP
}

// ---------------------------------------------------------------------------
// Kernel 3: bias + softmax over trailing dim of 8. One thread per row of 8.
// ---------------------------------------------------------------------------
__global__ void kan_softmax(const float* __restrict__ y, const float* __restrict__ bias,
                            float* __restrict__ out) {
  int g = blockIdx.x * blockDim.x + threadIdx.x;
  if (g >= BATCH * ACT / 8) return;
  int b = g >> 8;
  int grp = g & 255;
  const float* yp = y + (size_t)b * ACT + (size_t)grp * 8;
  const float* bp = bias + (size_t)grp * 8;
  float4 y0 = reinterpret_cast<const float4*>(yp)[0];
  float4 y1 = reinterpret_cast<const float4*>(yp)[1];
  float4 w0 = reinterpret_cast<const float4*>(bp)[0];
  float4 w1 = reinterpret_cast<const float4*>(bp)[1];
  float v[8] = {y0.x + w0.x, y0.y + w0.y, y0.z + w0.z, y0.w + w0.w,
                y1.x + w1.x, y1.y + w1.y, y1.z + w1.z, y1.w + w1.w};
  float mx = v[0];
#pragma unroll
  for (int j = 1; j < 8; ++j) mx = fmaxf(mx, v[j]);
  float s = 0.0f;
#pragma unroll
  for (int j = 0; j < 8; ++j) {
    v[j] = expf(v[j] - mx);
    s += v[j];
  }
  float inv = 1.0f / s;
  float* op = out + (size_t)b * ACT + (size_t)grp * 8;
  reinterpret_cast<float4*>(op)[0] = make_float4(v[0] * inv, v[1] * inv, v[2] * inv, v[3] * inv);
  reinterpret_cast<float4*>(op)[1] = make_float4(v[4] * inv, v[5] * inv, v[6] * inv, v[7] * inv);
}

// ---------------------------------------------------------------------------
// Workspace layout (floats):
//   y      @ 0        : 16384   (zeroed each call; atomicAdd target)
//   Bq     @ 16384    : 131072  ([ic][b*2+h][il] float4)
//   Bk     @ 147456   : 131072
//   baseq  @ 278528   : 16384   ([ic][b][il])
//   basek  @ 294912   : 16384
// total 311296 floats = 1.19 MiB
// ---------------------------------------------------------------------------
extern "C" void kernel_launch(void* const* d_in, const int* in_sizes, int n_in,
                              void* d_out, int out_size, void* d_ws, size_t ws_size,
                              hipStream_t stream) {
  const float* q          = (const float*)d_in[0];
  const float* k          = (const float*)d_in[1];
  const float* coef_q     = (const float*)d_in[2];
  const float* coef_k     = (const float*)d_in[3];
  const float* scale_base = (const float*)d_in[4];
  const float* scale_sp   = (const float*)d_in[5];
  const float* mask_q     = (const float*)d_in[6];
  const float* mask_k     = (const float*)d_in[7];
  const float* bias_w     = (const float*)d_in[8];
  float* out = (float*)d_out;

  float* ws    = (float*)d_ws;
  float* y     = ws;
  float* Bq    = ws + 16384;
  float* Bk    = Bq + 131072;
  float* baseq = Bk + 131072;
  float* basek = baseq + 16384;

  hipMemsetAsync(y, 0, 16384 * sizeof(float), stream);
  kan_precompute<<<dim3(64), dim3(256), 0, stream>>>(
      q, k, (float4*)Bq, (float4*)Bk, baseq, basek);
  kan_main<<<dim3(NOB * NIC), dim3(512), 0, stream>>>(
      coef_q, coef_k, scale_base, scale_sp, mask_q, mask_k,
      (const float4*)Bq, (const float4*)Bk, baseq, basek, y);
  kan_softmax<<<dim3(8), dim3(256), 0, stream>>>(y, bias_w, out);
}

// Round 4
// 203.693 us; speedup vs baseline: 2.6498x; 2.6498x over previous
//
#include <hip/hip_runtime.h>
#include <math.h>

// KAN attention: two spline-edge reductions (q,k branches) + bias + softmax(dim=8).
// batch=8, act_in=act_out=2048, C=8 coeffs/edge, N=4.19M edges/branch.
// HBM floor ~342 MB -> ~54 us at 6.3 TB/s achievable.
//
// R3 -> R4: R3 spilled (VGPR buffers > 128 under launch_bounds(512,4); 874 MB
// scratch writes). R4: 1024 fully-resident blocks (4/CU via 36KB LDS), one
// sync per block lifetime, 8 barrier-free steps, branches fused (scales read
// once), no atomics (shfl butterfly + plain stores to y_part), no in-thread
// double buffering (TLP from 16 waves/CU hides latency), #pragma unroll 1 on
// the step loop to keep VGPR ~95 < 128.

#define ACT 2048
#define BATCH 8
#define IBLK 64               // i per block (= lanes of one wave)
#define NIC (ACT / IBLK)      // 32 i-chunks
#define OBLK 64               // o per block
#define NOC (ACT / OBLK)      // 32 o-chunks

__device__ __forceinline__ float dot4(const float4& a, const float4& b) {
  float r = a.x * b.x;
  r = fmaf(a.y, b.y, r);
  r = fmaf(a.z, b.z, r);
  r = fmaf(a.w, b.w, r);
  return r;
}

// ---------------------------------------------------------------------------
// Kernel 1: B-spline basis (Cox-de Boor, k=3, 12 uniform knots at -2.2+0.4j)
// and silu(x) for all (b,i) of both branches.
// Layout: B[ic][b*2+h][il] as float4 (ic=i/64, il=i%64), base[ic][b][il].
// ---------------------------------------------------------------------------
__global__ void kan_precompute(const float* __restrict__ q, const float* __restrict__ k,
                               float4* __restrict__ Bq, float4* __restrict__ Bk,
                               float* __restrict__ baseq, float* __restrict__ basek) {
  int tid = blockIdx.x * blockDim.x + threadIdx.x;
  if (tid >= ACT * BATCH) return;
  int il = tid & (IBLK - 1);
  int b = (tid >> 6) & 7;
  int ic = tid >> 9;
  int i = ic * IBLK + il;
  const float t0 = -2.2f;
  const float h = 0.4f;
  for (int br = 0; br < 2; ++br) {
    const float* xsrc = br ? k : q;
    float4* Bdst = br ? Bk : Bq;
    float* basedst = br ? basek : baseq;
    float x = xsrc[(size_t)b * ACT + i];
    float Bv[11];
#pragma unroll
    for (int j = 0; j < 11; ++j) {
      float tj = t0 + h * (float)j;
      float tj1 = t0 + h * (float)(j + 1);
      Bv[j] = (x >= tj && x < tj1) ? 1.0f : 0.0f;
    }
#pragma unroll
    for (int d = 1; d <= 3; ++d) {
      float inv = 1.0f / (h * (float)d);
#pragma unroll
      for (int j = 0; j + d < 11; ++j) {
        float tj = t0 + h * (float)j;
        float tjd1 = t0 + h * (float)(j + d + 1);
        Bv[j] = (x - tj) * inv * Bv[j] + (tjd1 - x) * inv * Bv[j + 1];
      }
    }
    Bdst[((size_t)ic * 16 + b * 2 + 0) * IBLK + il] = make_float4(Bv[0], Bv[1], Bv[2], Bv[3]);
    Bdst[((size_t)ic * 16 + b * 2 + 1) * IBLK + il] = make_float4(Bv[4], Bv[5], Bv[6], Bv[7]);
    basedst[((size_t)ic * 8 + b) * IBLK + il] = x / (1.0f + expf(-x));
  }
}

// ---------------------------------------------------------------------------
// Kernel 2: main reduction. 1024 blocks x 256 threads, all resident (4/CU).
// Block = (ic: 64 i) x (oc: 64 o). Wave w (lane l = i) handles 2 o's per
// step, 8 steps. B/base for both branches staged to LDS once; the step loop
// has NO barriers. Per step: 16 VMEM loads (coef q/k for 2 o's + 8 scalars),
// b-loop reuses each LDS B row across 2 o's and both branches, 6-level
// shfl_xor butterfly, plain coalesced-ish stores to y_part[o][ic][b].
// ---------------------------------------------------------------------------
__global__ __launch_bounds__(256, 4) void kan_main(
    const float* __restrict__ coef_q, const float* __restrict__ coef_k,
    const float* __restrict__ scale_base, const float* __restrict__ scale_sp,
    const float* __restrict__ mask_q, const float* __restrict__ mask_k,
    const float4* __restrict__ Bq, const float4* __restrict__ Bk,
    const float* __restrict__ baseq, const float* __restrict__ basek,
    float* __restrict__ y_part) {
  __shared__ float4 BsQ[16 * IBLK];   // [(b*2+h)*64 + il]
  __shared__ float4 BsK[16 * IBLK];
  __shared__ float basQ[8 * IBLK];    // [b*64 + il]
  __shared__ float basK[8 * IBLK];

  const int t = threadIdx.x;
  const int l = t & 63;               // lane = i within chunk
  const int w = t >> 6;               // wave = o-group (0..3)
  const int oc = blockIdx.x >> 5;
  const int ic = blockIdx.x & 31;
  const int o0 = oc * OBLK;
  const size_t ibase = (size_t)ic * IBLK + l;

  // ---- stage B/base for both branches (once per block lifetime) ----
  {
    const float4* srcq = Bq + (size_t)ic * 16 * IBLK;
    const float4* srck = Bk + (size_t)ic * 16 * IBLK;
#pragma unroll
    for (int r = 0; r < 4; ++r) {
      BsQ[r * 256 + t] = srcq[r * 256 + t];
      BsK[r * 256 + t] = srck[r * 256 + t];
    }
    if (t < 128) {
      reinterpret_cast<float4*>(basQ)[t] =
          reinterpret_cast<const float4*>(baseq + (size_t)ic * 8 * IBLK)[t];
    } else {
      reinterpret_cast<float4*>(basK)[t - 128] =
          reinterpret_cast<const float4*>(basek + (size_t)ic * 8 * IBLK)[t - 128];
    }
  }
  __syncthreads();

#pragma unroll 1
  for (int s = 0; s < 8; ++s) {
    const int oa = o0 + s * 8 + w * 2;
    const size_t ea = (size_t)oa * ACT + ibase;
    const size_t eb = ea + ACT;

    // coef loads: 8 x dwordx4 (lane-stride 32 B, fully coalesced lines)
    const float4* cpa_q = reinterpret_cast<const float4*>(coef_q + ea * 8);
    const float4* cpb_q = reinterpret_cast<const float4*>(coef_q + eb * 8);
    const float4* cpa_k = reinterpret_cast<const float4*>(coef_k + ea * 8);
    const float4* cpb_k = reinterpret_cast<const float4*>(coef_k + eb * 8);
    float4 cqa0 = cpa_q[0], cqa1 = cpa_q[1];
    float4 cqb0 = cpb_q[0], cqb1 = cpb_q[1];
    float4 cka0 = cpa_k[0], cka1 = cpa_k[1];
    float4 ckb0 = cpb_k[0], ckb1 = cpb_k[1];
    // scalar loads: 8 x dword (lane-stride 4 B, coalesced)
    float mqa = mask_q[ea], mqb = mask_q[eb];
    float mka = mask_k[ea], mkb = mask_k[eb];
    float sba = scale_base[ea], sbb = scale_base[eb];
    float ssa = scale_sp[ea], ssb = scale_sp[eb];

    float vbqa = mqa * sba, vsqa = mqa * ssa, vbka = mka * sba, vska = mka * ssa;
    float vbqb = mqb * sbb, vsqb = mqb * ssb, vbkb = mkb * sbb, vskb = mkb * ssb;

    float acca[BATCH], accb[BATCH];
#pragma unroll
    for (int b = 0; b < BATCH; ++b) {
      const float4 Bq0 = BsQ[(b * 2 + 0) * IBLK + l];
      const float4 Bq1 = BsQ[(b * 2 + 1) * IBLK + l];
      const float4 Bk0 = BsK[(b * 2 + 0) * IBLK + l];
      const float4 Bk1 = BsK[(b * 2 + 1) * IBLK + l];
      const float bsq = basQ[b * IBLK + l];
      const float bsk = basK[b * IBLK + l];

      float dqa = dot4(Bq0, cqa0) + dot4(Bq1, cqa1);
      float dka = dot4(Bk0, cka0) + dot4(Bk1, cka1);
      float a = vsqa * dqa;
      a = fmaf(vska, dka, a);
      a = fmaf(vbqa, bsq, a);
      a = fmaf(vbka, bsk, a);
      acca[b] = a;

      float dqb = dot4(Bq0, cqb0) + dot4(Bq1, cqb1);
      float dkb = dot4(Bk0, ckb0) + dot4(Bk1, ckb1);
      float c = vsqb * dqb;
      c = fmaf(vskb, dkb, c);
      c = fmaf(vbqb, bsq, c);
      c = fmaf(vbkb, bsk, c);
      accb[b] = c;
    }

    // 6-level xor butterfly over the 64-lane i dim: all lanes get totals.
#pragma unroll
    for (int b = 0; b < BATCH; ++b) {
#pragma unroll
      for (int off = 1; off < 64; off <<= 1) {
        acca[b] += __shfl_xor(acca[b], off);
        accb[b] += __shfl_xor(accb[b], off);
      }
    }
    // lane l<8 stores b=l; select with compile-time-indexed cndmask chain
    // (runtime-indexed register arrays would go to scratch).
    float va = acca[0], vb = accb[0];
#pragma unroll
    for (int b = 1; b < BATCH; ++b) {
      va = (l == b) ? acca[b] : va;
      vb = (l == b) ? accb[b] : vb;
    }
    if (l < 8) {
      y_part[(size_t)oa * (NIC * 8) + ic * 8 + l] = va;
      y_part[(size_t)(oa + 1) * (NIC * 8) + ic * 8 + l] = vb;
    }
  }
}

// ---------------------------------------------------------------------------
// Kernel 3: sum 32 i-chunk partials per (o,b), add bias, softmax over groups
// of 8 outputs. One wave per output row (b,grp); 4 rows per 256-thread block.
// Lane l: o' = l>>3 (8 o's), sub = l&7 (partial-chunk slice).
// ---------------------------------------------------------------------------
__global__ void kan_softmax(const float* __restrict__ y_part,
                            const float* __restrict__ bias,
                            float* __restrict__ out) {
  const int t = threadIdx.x;
  const int wid = blockIdx.x * 4 + (t >> 6);   // row id, 0..2047
  const int b = wid >> 8;
  const int grp = wid & 255;
  const int l = t & 63;
  const int op = l >> 3;                       // o within group
  const int sub = l & 7;
  const int o = grp * 8 + op;

  float p = 0.0f;
#pragma unroll
  for (int j = 0; j < 4; ++j) {
    int icc = sub + 8 * j;
    p += y_part[(size_t)o * (NIC * 8) + icc * 8 + b];
  }
  // sum the 8 sub-partials within each o-group (lanes 8*op .. 8*op+7)
#pragma unroll
  for (int off = 1; off < 8; off <<= 1) p += __shfl_xor(p, off);
  float v = p + bias[o];
  // softmax across the 8 o-groups (xor offs 8,16,32 span the groups)
  float m = v;
#pragma unroll
  for (int off = 8; off < 64; off <<= 1) m = fmaxf(m, __shfl_xor(m, off));
  float e = expf(v - m);
  float ssum = e;
#pragma unroll
  for (int off = 8; off < 64; off <<= 1) ssum += __shfl_xor(ssum, off);
  if (sub == 0) out[(size_t)b * ACT + o] = e / ssum;
}

// ---------------------------------------------------------------------------
// Workspace layout (floats):
//   y_part @ 0      : 524288  ([o][ic][b], fully rewritten each call)
//   Bq     @ 524288 : 131072  ([ic][b*2+h][il] float4)
//   Bk     @ 655360 : 131072
//   baseq  @ 786432 : 16384   ([ic][b][il])
//   basek  @ 802816 : 16384
// total 819200 floats = 3.125 MiB. No init needed (every slot written).
// ---------------------------------------------------------------------------
extern "C" void kernel_launch(void* const* d_in, const int* in_sizes, int n_in,
                              void* d_out, int out_size, void* d_ws, size_t ws_size,
                              hipStream_t stream) {
  const float* q          = (const float*)d_in[0];
  const float* k          = (const float*)d_in[1];
  const float* coef_q     = (const float*)d_in[2];
  const float* coef_k     = (const float*)d_in[3];
  const float* scale_base = (const float*)d_in[4];
  const float* scale_sp   = (const float*)d_in[5];
  const float* mask_q     = (const float*)d_in[6];
  const float* mask_k     = (const float*)d_in[7];
  const float* bias_w     = (const float*)d_in[8];
  float* out = (float*)d_out;

  float* ws     = (float*)d_ws;
  float* y_part = ws;
  float* Bq     = ws + 524288;
  float* Bk     = Bq + 131072;
  float* baseq  = Bk + 131072;
  float* basek  = baseq + 16384;

  kan_precompute<<<dim3(64), dim3(256), 0, stream>>>(
      q, k, (float4*)Bq, (float4*)Bk, baseq, basek);
  kan_main<<<dim3(NOC * NIC), dim3(256), 0, stream>>>(
      coef_q, coef_k, scale_base, scale_sp, mask_q, mask_k,
      (const float4*)Bq, (const float4*)Bk, baseq, basek, y_part);
  kan_softmax<<<dim3(512), dim3(256), 0, stream>>>(y_part, bias_w, out);
}